// Round 6
// baseline (555.286 us; speedup 1.0000x reference)
//
#include <hip/hip_runtime.h>
#include <math.h>

constexpr int NE  = 16;   // experts
constexpr int NG  = 4;    // groups
constexpr int NSL = 4;    // k-slices = waves per block
constexpr int KS  = 16;   // k per iteration (64B x-line per token per step)
constexpr int TPB = 128;  // tokens per block (2 per lane)

// w transposed to [k][e] fp32: one expert-row per k = 64 B = one s_load_dwordx16
__global__ __launch_bounds__(256)
void w_transpose_kernel(const float* __restrict__ w, float* __restrict__ wt,
                        int dim, int n) {
    int id = blockIdx.x * 256 + threadIdx.x;
    if (id < n) {
        int k = id / NE;
        int e = id - k * NE;
        wt[id] = w[(size_t)e * dim + k];
    }
}

template <int WT>
__global__ __launch_bounds__(256)
void router_kernel(const float* __restrict__ x,
                   const float* __restrict__ w1w,
                   const float* __restrict__ wt,
                   const float* __restrict__ w1b,
                   const float* __restrict__ rbias,
                   float* __restrict__ dout,
                   int n_tokens, int dim)
{
    const int tid  = threadIdx.x;
    const int uwid = __builtin_amdgcn_readfirstlane(tid >> 6);  // uniform slice id
    const int lane = tid & 63;
    const int slice = dim / NSL;          // 1024
    const long t0  = (long)blockIdx.x * TPB;
    const long tokA = t0 + lane;
    const long tokB = tokA + 64;

    const float* xA = x + tokA * (size_t)dim + (size_t)uwid * slice;
    const float* xB = x + tokB * (size_t)dim + (size_t)uwid * slice;

    double accA[NE], accB[NE];
#pragma unroll
    for (int e = 0; e < NE; ++e) { accA[e] = 0.0; accB[e] = 0.0; }

    // prefetch first 64B line per token
    float4 a0 = *(const float4*)(xA + 0), a1 = *(const float4*)(xA + 4);
    float4 a2 = *(const float4*)(xA + 8), a3 = *(const float4*)(xA + 12);
    float4 b0 = *(const float4*)(xB + 0), b1 = *(const float4*)(xB + 4);
    float4 b2 = *(const float4*)(xB + 8), b3 = *(const float4*)(xB + 12);

    for (int k = 0; k < slice; k += KS) {
        float4 na0, na1, na2, na3, nb0, nb1, nb2, nb3;
        if (k + KS < slice) {
            const float* pa = xA + k + KS;
            const float* pb = xB + k + KS;
            na0 = *(const float4*)(pa + 0);  na1 = *(const float4*)(pa + 4);
            na2 = *(const float4*)(pa + 8);  na3 = *(const float4*)(pa + 12);
            nb0 = *(const float4*)(pb + 0);  nb1 = *(const float4*)(pb + 4);
            nb2 = *(const float4*)(pb + 8);  nb3 = *(const float4*)(pb + 12);
        } else {
            na0 = a0; na1 = a1; na2 = a2; na3 = a3;
            nb0 = b0; nb1 = b1; nb2 = b2; nb3 = b3;
        }

        float fa[KS], fb[KS];
        fa[0]=a0.x; fa[1]=a0.y; fa[2]=a0.z; fa[3]=a0.w;
        fa[4]=a1.x; fa[5]=a1.y; fa[6]=a1.z; fa[7]=a1.w;
        fa[8]=a2.x; fa[9]=a2.y; fa[10]=a2.z; fa[11]=a2.w;
        fa[12]=a3.x; fa[13]=a3.y; fa[14]=a3.z; fa[15]=a3.w;
        fb[0]=b0.x; fb[1]=b0.y; fb[2]=b0.z; fb[3]=b0.w;
        fb[4]=b1.x; fb[5]=b1.y; fb[6]=b1.z; fb[7]=b1.w;
        fb[8]=b2.x; fb[9]=b2.y; fb[10]=b2.z; fb[11]=b2.w;
        fb[12]=b3.x; fb[13]=b3.y; fb[14]=b3.z; fb[15]=b3.w;

#pragma unroll
        for (int kk = 0; kk < KS; ++kk) {
            double xa = (double)fa[kk];
            double xb = (double)fb[kk];
            if (WT) {
                const float* wr = wt + (size_t)(uwid * slice + k + kk) * NE; // uniform, 64B row
#pragma unroll
                for (int e = 0; e < NE; ++e) {
                    double wv = (double)wr[e];
                    accA[e] = fma(xa, wv, accA[e]);
                    accB[e] = fma(xb, wv, accB[e]);
                }
            } else {
                const int kb = uwid * slice + k + kk;                        // uniform
#pragma unroll
                for (int e = 0; e < NE; ++e) {
                    double wv = (double)w1w[(size_t)e * dim + kb];
                    accA[e] = fma(xa, wv, accA[e]);
                    accB[e] = fma(xb, wv, accB[e]);
                }
            }
        }
        a0=na0; a1=na1; a2=na2; a3=na3;
        b0=nb0; b1=nb1; b2=nb2; b3=nb3;
    }

    // ---- cross-wave (slice) reduction: waves 1..3 park partials in LDS ----
    __shared__ double red[NSL - 1][2][64][NE + 1];   // 52224 B
    if (uwid != 0) {
#pragma unroll
        for (int e = 0; e < NE; ++e) {
            red[uwid - 1][0][lane][e] = accA[e];
            red[uwid - 1][1][lane][e] = accB[e];
        }
    }
    __syncthreads();
    if (uwid != 0) return;

#pragma unroll
    for (int t = 0; t < 2; ++t) {
        double tot[NE];
#pragma unroll
        for (int e = 0; e < NE; ++e) {
            double a = (t == 0) ? accA[e] : accB[e];
            tot[e] = ((a + red[0][t][lane][e]) + red[1][t][lane][e])
                     + red[2][t][lane][e];
        }

        // ---- fp64 epilogue: softmax + bias + group-limited top-2 ----
        double logit[NE];
        double m = -INFINITY;
#pragma unroll
        for (int e = 0; e < NE; ++e) {
            logit[e] = tot[e] + (double)w1b[e];
            m = fmax(m, logit[e]);
        }
        double ssum = 0.0;
        double p[NE];
#pragma unroll
        for (int e = 0; e < NE; ++e) { p[e] = exp(logit[e] - m); ssum += p[e]; }
        double inv = 1.0 / ssum;
        double sc[NE];
#pragma unroll
        for (int e = 0; e < NE; ++e) sc[e] = p[e] * inv + (double)rbias[e];

        double gm[NG];
#pragma unroll
        for (int g = 0; g < NG; ++g) {
            double a = fmax(sc[g * 4 + 0], sc[g * 4 + 1]);
            double b = fmax(sc[g * 4 + 2], sc[g * 4 + 3]);
            gm[g] = fmax(a, b);
        }
        int g1 = 0;
#pragma unroll
        for (int g = 1; g < NG; ++g) if (gm[g] > gm[g1]) g1 = g;
        int g2 = (g1 == 0) ? 1 : 0;
#pragma unroll
        for (int g = 0; g < NG; ++g) if (g != g1 && gm[g] > gm[g2]) g2 = g;

        double v1 = -INFINITY; int i1 = 0;
#pragma unroll
        for (int e = 0; e < NE; ++e) {
            int g = e >> 2;
            bool keep = (g == g1) || (g == g2);
            if (keep && sc[e] > v1) { v1 = sc[e]; i1 = e; }
        }
        double v2 = -INFINITY; int i2 = 0;
#pragma unroll
        for (int e = 0; e < NE; ++e) {
            int g = e >> 2;
            bool keep = ((g == g1) || (g == g2)) && (e != i1);
            if (keep && sc[e] > v2) { v2 = sc[e]; i2 = e; }
        }

        long tok = (t == 0) ? tokA : tokB;
        float2 vv; vv.x = (float)v1; vv.y = (float)v2;
        *(float2*)(dout + tok * 2) = vv;
        float2 iv; iv.x = (float)i1; iv.y = (float)i2;
        *(float2*)(dout + (long)n_tokens * 2 + tok * 2) = iv;
    }
}

extern "C" void kernel_launch(void* const* d_in, const int* in_sizes, int n_in,
                              void* d_out, int out_size, void* d_ws, size_t ws_size,
                              hipStream_t stream)
{
    const float* x   = (const float*)d_in[0];
    const float* w1w = (const float*)d_in[1];
    const float* w1b = (const float*)d_in[2];
    const float* rb  = (const float*)d_in[3];
    float* out = (float*)d_out;

    const int ne       = in_sizes[2];            // 16
    const int dim      = in_sizes[1] / ne;       // 4096
    const int n_tokens = in_sizes[0] / dim;      // 65536

    const int nW = dim * ne;                     // 65536 w elements
    const bool useT = ws_size >= (size_t)nW * sizeof(float);

    dim3 grid(n_tokens / TPB), block(NSL * 64);
    if (useT) {
        float* wt = (float*)d_ws;
        hipLaunchKernelGGL(w_transpose_kernel, dim3((nW + 255) / 256), dim3(256),
                           0, stream, w1w, wt, dim, nW);
        hipLaunchKernelGGL((router_kernel<1>), grid, block, 0, stream,
                           x, w1w, (const float*)wt, w1b, rb, out, n_tokens, dim);
    } else {
        hipLaunchKernelGGL((router_kernel<0>), grid, block, 0, stream,
                           x, w1w, (const float*)nullptr, w1b, rb, out, n_tokens, dim);
    }
}

// Round 7
// 341.861 us; speedup vs baseline: 1.6243x; 1.6243x over previous
//
#include <hip/hip_runtime.h>
#include <math.h>

constexpr int NE  = 16;   // experts
constexpr int NG  = 4;    // groups
constexpr int NSL = 4;    // k-slices = waves per block
constexpr int KS  = 16;   // k per step (1 KB w-chunk, 64 B x per lane)
constexpr int TOK = 64;   // tokens per block (one per lane)
// LDS: staging wbuf[4][16][16] f64 = 8192 B; reduction area 3*64*17*8 = 26112 B (aliased)
constexpr int LDS_BYTES = 26112;

__global__ __launch_bounds__(256)
void w_transpose_kernel(const float* __restrict__ w, float* __restrict__ wt,
                        int dim, int n) {
    int id = blockIdx.x * 256 + threadIdx.x;
    if (id < n) {
        int k = id / NE;
        int e = id - k * NE;
        wt[id] = w[(size_t)e * dim + k];   // [k][e] fp32
    }
}

template <int WT>
__global__ __launch_bounds__(256)
void router_kernel(const float* __restrict__ x,
                   const float* __restrict__ w1w,
                   const float* __restrict__ wt,
                   const float* __restrict__ w1b,
                   const float* __restrict__ rbias,
                   float* __restrict__ dout,
                   int n_tokens, int dim)
{
    __shared__ char ldsraw[LDS_BYTES];
    auto wbuf = (double (*)[KS][NE])ldsraw;      // [wave][kk][e]

    const int tid  = threadIdx.x;
    const int uwid = __builtin_amdgcn_readfirstlane(tid >> 6);  // uniform slice id
    const int lane = tid & 63;
    const int slice = dim / NSL;          // 1024
    const int nst  = slice / KS;          // 64 steps
    const long tok = (long)blockIdx.x * TOK + lane;

    const float* xp = x + tok * (size_t)dim + (size_t)uwid * slice;

    double acc[NE];
#pragma unroll
    for (int e = 0; e < NE; ++e) acc[e] = 0.0;

    // ---- prologue: load step 0 (x regs + w fp32 coop chunk) ----
    float4 c0 = *(const float4*)(xp + 0),  c1 = *(const float4*)(xp + 4);
    float4 c2 = *(const float4*)(xp + 8),  c3 = *(const float4*)(xp + 12);

    float4 wreg;
    if (WT) {
        const float* wtp = wt + (size_t)uwid * slice * NE;      // [k][e] fp32
        wreg = *(const float4*)(wtp + lane * 4);                // 1 KB coop load
    } else {
        // fallback: gather from original [e][dim] layout (4 scattered loads)
        const int i0 = lane * 4;
#pragma unroll
        for (int j = 0; j < 4; ++j) {
            int i = i0 + j;
            ((float*)&wreg)[j] = w1w[(size_t)(i & 15) * dim + uwid * slice + (i >> 4)];
        }
    }

    for (int c = 0; c < nst; ++c) {
        // stage w chunk c into LDS as fp64 (convert ONCE; wave-ordered DS, no barrier)
        {
            double* dst = &wbuf[uwid][0][0] + lane * 4;
            dst[0] = (double)wreg.x;  dst[1] = (double)wreg.y;
            dst[2] = (double)wreg.z;  dst[3] = (double)wreg.w;
        }

        // prefetch step c+1 (latency hides under this step's FMAs)
        float4 n0 = c0, n1 = c1, n2 = c2, n3 = c3;
        if (c + 1 < nst) {
            const float* xn = xp + (c + 1) * KS;
            n0 = *(const float4*)(xn + 0);  n1 = *(const float4*)(xn + 4);
            n2 = *(const float4*)(xn + 8);  n3 = *(const float4*)(xn + 12);
            if (WT) {
                const float* wtp = wt + (size_t)(uwid * slice + (c + 1) * KS) * NE;
                wreg = *(const float4*)(wtp + lane * 4);
            } else {
                const int kb = uwid * slice + (c + 1) * KS;
                const int i0 = lane * 4;
#pragma unroll
                for (int j = 0; j < 4; ++j) {
                    int i = i0 + j;
                    ((float*)&wreg)[j] = w1w[(size_t)(i & 15) * dim + kb + (i >> 4)];
                }
            }
        }

        float fx[KS];
        fx[0]=c0.x;  fx[1]=c0.y;  fx[2]=c0.z;  fx[3]=c0.w;
        fx[4]=c1.x;  fx[5]=c1.y;  fx[6]=c1.z;  fx[7]=c1.w;
        fx[8]=c2.x;  fx[9]=c2.y;  fx[10]=c2.z; fx[11]=c2.w;
        fx[12]=c3.x; fx[13]=c3.y; fx[14]=c3.z; fx[15]=c3.w;

        // FMAs: w via uniform-address LDS reads (broadcast, conflict-free)
#pragma unroll
        for (int kk = 0; kk < KS; ++kk) {
            double xv = (double)fx[kk];
            const double* wr = &wbuf[uwid][kk][0];
#pragma unroll
            for (int e = 0; e < NE; ++e)
                acc[e] = fma(xv, wr[e], acc[e]);
        }

        c0 = n0; c1 = n1; c2 = n2; c3 = n3;
    }

    // ---- cross-wave (slice) reduction: waves 1..3 park partials in LDS ----
    __syncthreads();                               // before aliasing wbuf
    auto red = (double (*)[TOK][NE + 1])ldsraw;    // [3][64][17]
    if (uwid != 0) {
#pragma unroll
        for (int e = 0; e < NE; ++e) red[uwid - 1][lane][e] = acc[e];
    }
    __syncthreads();
    if (uwid != 0) return;

    double tot[NE];
#pragma unroll
    for (int e = 0; e < NE; ++e)
        tot[e] = ((acc[e] + red[0][lane][e]) + red[1][lane][e]) + red[2][lane][e];

    // ---- fp64 epilogue: softmax + bias + group-limited top-2 ----
    double logit[NE];
    double m = -INFINITY;
#pragma unroll
    for (int e = 0; e < NE; ++e) {
        logit[e] = tot[e] + (double)w1b[e];
        m = fmax(m, logit[e]);
    }
    double ssum = 0.0;
    double p[NE];
#pragma unroll
    for (int e = 0; e < NE; ++e) { p[e] = exp(logit[e] - m); ssum += p[e]; }
    double inv = 1.0 / ssum;
    double sc[NE];
#pragma unroll
    for (int e = 0; e < NE; ++e) sc[e] = p[e] * inv + (double)rbias[e];

    double gm[NG];
#pragma unroll
    for (int g = 0; g < NG; ++g) {
        double a = fmax(sc[g * 4 + 0], sc[g * 4 + 1]);
        double b = fmax(sc[g * 4 + 2], sc[g * 4 + 3]);
        gm[g] = fmax(a, b);
    }
    int g1 = 0;
#pragma unroll
    for (int g = 1; g < NG; ++g) if (gm[g] > gm[g1]) g1 = g;
    int g2 = (g1 == 0) ? 1 : 0;
#pragma unroll
    for (int g = 0; g < NG; ++g) if (g != g1 && gm[g] > gm[g2]) g2 = g;

    double v1 = -INFINITY; int i1 = 0;
#pragma unroll
    for (int e = 0; e < NE; ++e) {
        int g = e >> 2;
        bool keep = (g == g1) || (g == g2);
        if (keep && sc[e] > v1) { v1 = sc[e]; i1 = e; }
    }
    double v2 = -INFINITY; int i2 = 0;
#pragma unroll
    for (int e = 0; e < NE; ++e) {
        int g = e >> 2;
        bool keep = ((g == g1) || (g == g2)) && (e != i1);
        if (keep && sc[e] > v2) { v2 = sc[e]; i2 = e; }
    }

    float2 vv; vv.x = (float)v1; vv.y = (float)v2;
    *(float2*)(dout + tok * 2) = vv;
    float2 iv; iv.x = (float)i1; iv.y = (float)i2;
    *(float2*)(dout + (long)n_tokens * 2 + tok * 2) = iv;
}

extern "C" void kernel_launch(void* const* d_in, const int* in_sizes, int n_in,
                              void* d_out, int out_size, void* d_ws, size_t ws_size,
                              hipStream_t stream)
{
    const float* x   = (const float*)d_in[0];
    const float* w1w = (const float*)d_in[1];
    const float* w1b = (const float*)d_in[2];
    const float* rb  = (const float*)d_in[3];
    float* out = (float*)d_out;

    const int ne       = in_sizes[2];            // 16
    const int dim      = in_sizes[1] / ne;       // 4096
    const int n_tokens = in_sizes[0] / dim;      // 65536

    const int nW = dim * ne;                     // 65536 w elements
    const bool useT = ws_size >= (size_t)nW * sizeof(float);

    dim3 grid(n_tokens / TOK), block(NSL * 64);
    if (useT) {
        float* wt = (float*)d_ws;
        hipLaunchKernelGGL(w_transpose_kernel, dim3((nW + 255) / 256), dim3(256),
                           0, stream, w1w, wt, dim, nW);
        hipLaunchKernelGGL((router_kernel<1>), grid, block, 0, stream,
                           x, w1w, (const float*)wt, w1b, rb, out, n_tokens, dim);
    } else {
        hipLaunchKernelGGL((router_kernel<0>), grid, block, 0, stream,
                           x, w1w, (const float*)nullptr, w1b, rb, out, n_tokens, dim);
    }
}

// Round 9
// 297.095 us; speedup vs baseline: 1.8691x; 1.1507x over previous
//
#include <hip/hip_runtime.h>
#include <math.h>

constexpr int NE  = 16;   // experts
constexpr int NG  = 4;    // groups
constexpr int NSL = 4;    // k-slices = waves per block
constexpr int KS  = 16;   // k per step (w-chunk 16x16 f64 in LDS)
constexpr int TPB = 128;  // tokens per block (2 per lane)
// LDS: wbuf[4][16][16] f64 = 8192 B; reduction red[3][2][64][17] f64 = 52224 B (aliased)
constexpr int LDS_BYTES = 52224;

__global__ __launch_bounds__(256)
void w_transpose_kernel(const float* __restrict__ w, float* __restrict__ wt,
                        int dim, int n) {
    int id = blockIdx.x * 256 + threadIdx.x;
    if (id < n) {
        int k = id / NE;
        int e = id - k * NE;
        wt[id] = w[(size_t)e * dim + k];   // [k][e] fp32
    }
}

template <int WT>
__global__ __launch_bounds__(256)
void router_kernel(const float* __restrict__ x,
                   const float* __restrict__ w1w,
                   const float* __restrict__ wt,
                   const float* __restrict__ w1b,
                   const float* __restrict__ rbias,
                   float* __restrict__ dout,
                   int n_tokens, int dim)
{
    __shared__ char ldsraw[LDS_BYTES];
    auto wbuf = (double (*)[KS][NE])ldsraw;      // [wave][kk][e]

    const int tid  = threadIdx.x;
    const int uwid = __builtin_amdgcn_readfirstlane(tid >> 6);  // uniform slice id
    const int lane = tid & 63;
    const int slice = dim / NSL;          // 1024
    const int nst  = slice / KS;          // 64 steps
    const long tokA = (long)blockIdx.x * TPB + lane;
    const long tokB = tokA + 64;

    const float* xA = x + tokA * (size_t)dim + (size_t)uwid * slice;
    const float* xB = x + tokB * (size_t)dim + (size_t)uwid * slice;

    double accA[NE], accB[NE];
#pragma unroll
    for (int e = 0; e < NE; ++e) { accA[e] = 0.0; accB[e] = 0.0; }

    // ---- prologue: step-0 x lines + w fp32 coop chunk ----
    float4 a0 = *(const float4*)(xA + 0),  a1 = *(const float4*)(xA + 4);
    float4 a2 = *(const float4*)(xA + 8),  a3 = *(const float4*)(xA + 12);
    float4 b0 = *(const float4*)(xB + 0),  b1 = *(const float4*)(xB + 4);
    float4 b2 = *(const float4*)(xB + 8),  b3 = *(const float4*)(xB + 12);

    float4 wreg;
    if (WT) {
        wreg = *(const float4*)(wt + (size_t)uwid * slice * NE + lane * 4);
    } else {
        const int i0 = lane * 4;
#pragma unroll
        for (int j = 0; j < 4; ++j) {
            int i = i0 + j;
            ((float*)&wreg)[j] = w1w[(size_t)(i & 15) * dim + uwid * slice + (i >> 4)];
        }
    }

    for (int c = 0; c < nst; ++c) {
        // stage w chunk c into LDS as fp64 (convert ONCE; wave-ordered DS)
        {
            double* dst = &wbuf[uwid][0][0] + lane * 4;
            dst[0] = (double)wreg.x;  dst[1] = (double)wreg.y;
            dst[2] = (double)wreg.z;  dst[3] = (double)wreg.w;
        }

        // prefetch step c+1 (x for both tokens + w chunk)
        float4 na0 = a0, na1 = a1, na2 = a2, na3 = a3;
        float4 nb0 = b0, nb1 = b1, nb2 = b2, nb3 = b3;
        if (c + 1 < nst) {
            const float* pa = xA + (c + 1) * KS;
            const float* pb = xB + (c + 1) * KS;
            na0 = *(const float4*)(pa + 0);  na1 = *(const float4*)(pa + 4);
            na2 = *(const float4*)(pa + 8);  na3 = *(const float4*)(pa + 12);
            nb0 = *(const float4*)(pb + 0);  nb1 = *(const float4*)(pb + 4);
            nb2 = *(const float4*)(pb + 8);  nb3 = *(const float4*)(pb + 12);
            if (WT) {
                wreg = *(const float4*)(wt + (size_t)(uwid * slice + (c + 1) * KS) * NE
                                        + lane * 4);
            } else {
                const int kb = uwid * slice + (c + 1) * KS;
                const int i0 = lane * 4;
#pragma unroll
                for (int j = 0; j < 4; ++j) {
                    int i = i0 + j;
                    ((float*)&wreg)[j] = w1w[(size_t)(i & 15) * dim + kb + (i >> 4)];
                }
            }
        }

        float fa[KS], fb[KS];
        fa[0]=a0.x;  fa[1]=a0.y;  fa[2]=a0.z;  fa[3]=a0.w;
        fa[4]=a1.x;  fa[5]=a1.y;  fa[6]=a1.z;  fa[7]=a1.w;
        fa[8]=a2.x;  fa[9]=a2.y;  fa[10]=a2.z; fa[11]=a2.w;
        fa[12]=a3.x; fa[13]=a3.y; fa[14]=a3.z; fa[15]=a3.w;
        fb[0]=b0.x;  fb[1]=b0.y;  fb[2]=b0.z;  fb[3]=b0.w;
        fb[4]=b1.x;  fb[5]=b1.y;  fb[6]=b1.z;  fb[7]=b1.w;
        fb[8]=b2.x;  fb[9]=b2.y;  fb[10]=b2.z; fb[11]=b2.w;
        fb[12]=b3.x; fb[13]=b3.y; fb[14]=b3.z; fb[15]=b3.w;

        // FMAs: each broadcast double2 LDS read feeds BOTH tokens (DS/FMA = 1/4)
#pragma unroll
        for (int kk = 0; kk < KS; ++kk) {
            double xa_ = (double)fa[kk];
            double xb_ = (double)fb[kk];
#pragma unroll
            for (int ep = 0; ep < NE / 2; ++ep) {
                double2 wv = *(const double2*)&wbuf[uwid][kk][ep * 2];
                accA[ep * 2 + 0] = fma(xa_, wv.x, accA[ep * 2 + 0]);
                accA[ep * 2 + 1] = fma(xa_, wv.y, accA[ep * 2 + 1]);
                accB[ep * 2 + 0] = fma(xb_, wv.x, accB[ep * 2 + 0]);
                accB[ep * 2 + 1] = fma(xb_, wv.y, accB[ep * 2 + 1]);
            }
        }

        a0=na0; a1=na1; a2=na2; a3=na3;
        b0=nb0; b1=nb1; b2=nb2; b3=nb3;
    }

    // ---- cross-wave (slice) reduction: waves 1..3 park partials in LDS ----
    __syncthreads();                                   // all wbuf reads done
    auto red = (double (*)[2][64][NE + 1])ldsraw;      // [3][2][64][17]
    if (uwid != 0) {
#pragma unroll
        for (int e = 0; e < NE; ++e) {
            red[uwid - 1][0][lane][e] = accA[e];
            red[uwid - 1][1][lane][e] = accB[e];
        }
    }
    __syncthreads();
    if (uwid != 0) return;

#pragma unroll
    for (int t = 0; t < 2; ++t) {
        double tot[NE];
#pragma unroll
        for (int e = 0; e < NE; ++e) {
            double a = (t == 0) ? accA[e] : accB[e];
            tot[e] = ((a + red[0][t][lane][e]) + red[1][t][lane][e])
                     + red[2][t][lane][e];
        }

        // ---- fp64 epilogue: softmax + bias + group-limited top-2 ----
        double logit[NE];
        double m = -INFINITY;
#pragma unroll
        for (int e = 0; e < NE; ++e) {
            logit[e] = tot[e] + (double)w1b[e];
            m = fmax(m, logit[e]);
        }
        double ssum = 0.0;
        double p[NE];
#pragma unroll
        for (int e = 0; e < NE; ++e) { p[e] = exp(logit[e] - m); ssum += p[e]; }
        double inv = 1.0 / ssum;
        double sc[NE];
#pragma unroll
        for (int e = 0; e < NE; ++e) sc[e] = p[e] * inv + (double)rbias[e];

        double gm[NG];
#pragma unroll
        for (int g = 0; g < NG; ++g) {
            double a = fmax(sc[g * 4 + 0], sc[g * 4 + 1]);
            double b = fmax(sc[g * 4 + 2], sc[g * 4 + 3]);
            gm[g] = fmax(a, b);
        }
        int g1 = 0;
#pragma unroll
        for (int g = 1; g < NG; ++g) if (gm[g] > gm[g1]) g1 = g;
        int g2 = (g1 == 0) ? 1 : 0;
#pragma unroll
        for (int g = 0; g < NG; ++g) if (g != g1 && gm[g] > gm[g2]) g2 = g;

        double v1 = -INFINITY; int i1 = 0;
#pragma unroll
        for (int e = 0; e < NE; ++e) {
            int g = e >> 2;
            bool keep = (g == g1) || (g == g2);
            if (keep && sc[e] > v1) { v1 = sc[e]; i1 = e; }
        }
        double v2 = -INFINITY; int i2 = 0;
#pragma unroll
        for (int e = 0; e < NE; ++e) {
            int g = e >> 2;
            bool keep = ((g == g1) || (g == g2)) && (e != i1);
            if (keep && sc[e] > v2) { v2 = sc[e]; i2 = e; }
        }

        long tok = (t == 0) ? tokA : tokB;
        float2 vv; vv.x = (float)v1; vv.y = (float)v2;
        *(float2*)(dout + tok * 2) = vv;
        float2 iv; iv.x = (float)i1; iv.y = (float)i2;
        *(float2*)(dout + (long)n_tokens * 2 + tok * 2) = iv;
    }
}

extern "C" void kernel_launch(void* const* d_in, const int* in_sizes, int n_in,
                              void* d_out, int out_size, void* d_ws, size_t ws_size,
                              hipStream_t stream)
{
    const float* x   = (const float*)d_in[0];
    const float* w1w = (const float*)d_in[1];
    const float* w1b = (const float*)d_in[2];
    const float* rb  = (const float*)d_in[3];
    float* out = (float*)d_out;

    const int ne       = in_sizes[2];            // 16
    const int dim      = in_sizes[1] / ne;       // 4096
    const int n_tokens = in_sizes[0] / dim;      // 65536

    const int nW = dim * ne;                     // 65536 w elements
    const bool useT = ws_size >= (size_t)nW * sizeof(float);

    dim3 grid(n_tokens / TPB), block(NSL * 64);
    if (useT) {
        float* wt = (float*)d_ws;
        hipLaunchKernelGGL(w_transpose_kernel, dim3((nW + 255) / 256), dim3(256),
                           0, stream, w1w, wt, dim, nW);
        hipLaunchKernelGGL((router_kernel<1>), grid, block, 0, stream,
                           x, w1w, (const float*)wt, w1b, rb, out, n_tokens, dim);
    } else {
        hipLaunchKernelGGL((router_kernel<0>), grid, block, 0, stream,
                           x, w1w, (const float*)nullptr, w1b, rb, out, n_tokens, dim);
    }
}